// Round 7
// baseline (763.090 us; speedup 1.0000x reference)
//
#include <hip/hip_runtime.h>
#include <hip/hip_bf16.h>

typedef __hip_bfloat16 bf16;
typedef __attribute__((ext_vector_type(8))) short short8;
typedef __attribute__((ext_vector_type(4))) float f32x4;

// ---- problem constants (fixed by reference file) ----
#define N_NODES 50000
#define N_EDGES 800000
#define IN_F    128
#define HID     256
#define N_CLS   10
#define N_GRAPH 256

#define AGG_CHUNK 64   // nodes per work item in panel agg kernels
#define AGG_GRID  2048

// flags[0] = ints are int64 (read low words), flags[1] = floats are bf16
__device__ __forceinline__ int IG(const int* __restrict__ p, int i, int w) {
    return w ? p[2 * i] : p[i];
}
__device__ __forceinline__ float LF(const void* __restrict__ p, int i, int isbf) {
    return isbf ? __bfloat162float(((const bf16*)p)[i]) : ((const float*)p)[i];
}
__device__ __forceinline__ float b2f(unsigned short h) {
    union { unsigned u; float f; } c; c.u = ((unsigned)h) << 16; return c.f;
}
__device__ __forceinline__ unsigned short f2b(float x) {
    bf16 h = __float2bfloat16(x);
    union { bf16 b; unsigned short u; } c; c.b = h; return c.u;
}
// HW_REG_XCC_ID = id 20, offset 0, width 4  ->  simm16 = ((4-1)<<11) | (0<<6) | 20
__device__ __forceinline__ int my_xcd() {
    return (int)(__builtin_amdgcn_s_getreg((3 << 11) | 20) & 7);
}

// ---- combined dtype detectors (1 block) ----
__global__ __launch_bounds__(256) void k_detect(const int* __restrict__ ei,
                                                const unsigned short* __restrict__ x,
                                                int* __restrict__ flags) {
    __shared__ int nz, cnt;
    if (threadIdx.x == 0) { nz = 0; cnt = 0; }
    __syncthreads();
    int found = 0, c = 0;
    for (int s = 0; s < 4; ++s) {
        int idx = 2 * (threadIdx.x * 4 + s) + 1;
        if (ei[idx] != 0) found = 1;
    }
    for (int s = 0; s < 8; ++s) {
        unsigned short h = x[threadIdx.x * 8 + s];
        int e = (h >> 7) & 0xFF;
        if (e >= 110 && e <= 135) c++;
    }
    if (found) atomicAdd(&nz, 1);
    atomicAdd(&cnt, c);
    __syncthreads();
    if (threadIdx.x == 0) {
        flags[0] = (nz == 0) ? 1 : 0;
        flags[1] = (cnt > 1536) ? 1 : 0;
    }
}

// ---- degree count over dst, privatized 8-way by pseudo-XCD = blockIdx&7 ----
__global__ __launch_bounds__(256) void k_deg(const int* __restrict__ ei, int* __restrict__ deg8,
                                             const int* __restrict__ flags, int E, int N) {
    int e = blockIdx.x * 256 + threadIdx.x;
    int w = flags[0];
    int px = blockIdx.x & 7;
    if (e < E) {
        int d = IG(ei, E + e, w);
        int s = IG(ei, e, w);
        if ((unsigned)d < (unsigned)N && (unsigned)s < (unsigned)N)
            atomicAdd(&deg8[px * N + d], 1);
    }
}

// ---- sum deg8 -> deg, dinv; plus graph boundaries from sorted batch ----
__global__ __launch_bounds__(256) void k_sum(const int* __restrict__ deg8, int* __restrict__ deg,
                                             float* __restrict__ dinv, const int* __restrict__ batch,
                                             const int* __restrict__ flags, int* __restrict__ gstart,
                                             int N, int G) {
    int i = blockIdx.x * 256 + threadIdx.x;
    int w = flags[0];
    if (i < N) {
        int d = 0;
#pragma unroll
        for (int x = 0; x < 8; ++x) d += deg8[x * N + i];
        deg[i] = d;
        dinv[i] = rsqrtf((float)(d + 1));  // +1 self loop
    }
    if (i <= N) {
        int prev = (i == 0) ? -1 : IG(batch, i - 1, w);
        int cur  = (i == N) ? G : IG(batch, i, w);
        if (prev < -1) prev = -1;
        if (cur > G) cur = G;
        for (int g = prev + 1; g <= cur; ++g)
            if (g >= 0 && g <= G) gstart[g] = i;
    }
}

// ---- exclusive scan over degrees ----
__global__ __launch_bounds__(256) void k_scan1(const int* __restrict__ deg, int* __restrict__ rowptr,
                                               int* __restrict__ blockSum, int N) {
    __shared__ int s[256];
    int t = threadIdx.x;
    int i = blockIdx.x * 256 + t;
    int v = (i < N) ? deg[i] : 0;
    s[t] = v;
    __syncthreads();
    for (int off = 1; off < 256; off <<= 1) {
        int add = (t >= off) ? s[t - off] : 0;
        __syncthreads();
        s[t] += add;
        __syncthreads();
    }
    if (i < N) rowptr[i] = s[t] - v;
    if (t == 255) blockSum[blockIdx.x] = s[t];
}

__global__ __launch_bounds__(256) void k_scan2(const int* __restrict__ blockSum, int* __restrict__ blockOff,
                                               int* __restrict__ total, int nb) {
    __shared__ int s[256];
    int t = threadIdx.x;
    int v = (t < nb) ? blockSum[t] : 0;
    s[t] = v;
    __syncthreads();
    for (int off = 1; off < 256; off <<= 1) {
        int add = (t >= off) ? s[t - off] : 0;
        __syncthreads();
        s[t] += add;
        __syncthreads();
    }
    blockOff[t] = s[t] - v;
    if (t == 255) total[0] = s[255];
}

__global__ __launch_bounds__(256) void k_scan3(int* __restrict__ rowptr, const int* __restrict__ blockOff,
                                               int N, const int* __restrict__ total) {
    int i = blockIdx.x * 256 + threadIdx.x;
    if (i < N) rowptr[i] += blockOff[blockIdx.x];
    if (i == 0) rowptr[N] = total[0];
}

// ---- per-(pseudo-xcd,node) fill bases: base8[x][i] = rowptr[i] + sum_{y<x} deg8[y][i] ----
__global__ __launch_bounds__(256) void k_base(const int* __restrict__ rowptr, const int* __restrict__ deg8,
                                              int* __restrict__ base8, int N) {
    int i = blockIdx.x * 256 + threadIdx.x;
    if (i >= N) return;
    int b = rowptr[i];
#pragma unroll
    for (int x = 0; x < 8; ++x) {
        base8[x * N + i] = b;
        b += deg8[x * N + i];
    }
}

// ---- CSR fill: position from privatized base (local atomics only) ----
__global__ __launch_bounds__(256) void k_fill(const int* __restrict__ ei, int* __restrict__ base8,
                                              int* __restrict__ col, const int* __restrict__ flags,
                                              int E, int N) {
    int e = blockIdx.x * 256 + threadIdx.x;
    int w = flags[0];
    int px = blockIdx.x & 7;
    if (e < E) {
        int d = IG(ei, E + e, w);
        int s = IG(ei, e, w);
        if ((unsigned)d < (unsigned)N && (unsigned)s < (unsigned)N) {
            int pos = atomicAdd(&base8[px * N + d], 1);
            col[pos] = s;
        }
    }
}

// ---- convert x to bf16 PRE-SCALED by dinv[row] ----
__global__ __launch_bounds__(256) void k_cvtx(const void* __restrict__ x, const float* __restrict__ dinv,
                                              unsigned short* __restrict__ out, const int* __restrict__ flags,
                                              int n4) {
    int gid = blockIdx.x * 256 + threadIdx.x;
    if (gid >= n4) return;
    int row = gid >> 5;  // IN_F/4 == 32 chunks per row
    float d = dinv[row];
    ushort4 o;
    if (flags[1]) {
        ushort4 v = ((const ushort4*)x)[gid];
        o.x = f2b(b2f(v.x) * d); o.y = f2b(b2f(v.y) * d);
        o.z = f2b(b2f(v.z) * d); o.w = f2b(b2f(v.w) * d);
    } else {
        float4 v = ((const float4*)x)[gid];
        o.x = f2b(v.x * d); o.y = f2b(v.y * d);
        o.z = f2b(v.z * d); o.w = f2b(v.w * d);
    }
    ((ushort4*)out)[gid] = o;
}

// ---- convert + transpose weight W[K x 256] -> Wt[256 x K] bf16 ----
__global__ __launch_bounds__(256) void k_cvtT(const void* __restrict__ in, unsigned short* __restrict__ out,
                                              const int* __restrict__ flags, int K, int kshift) {
    int i = blockIdx.x * 256 + threadIdx.x;
    if (i >= K * 256) return;
    int n = i >> kshift;
    int k = i & (K - 1);
    out[i] = f2b(LF(in, k * 256 + n, flags[1]));
}

// ---- bf16 MFMA GEMM: C[M x 256] = A[M x K] @ B[K x 256] with fused epilogue ----
__global__ __launch_bounds__(256) void k_gemm(const unsigned short* __restrict__ A,
                                              const unsigned short* __restrict__ Bt,
                                              unsigned short* __restrict__ C, int M, int K,
                                              const float* __restrict__ rowscale,
                                              const void* __restrict__ bias,
                                              const int* __restrict__ flags, int relu) {
    __shared__ unsigned short As[64 * 40];
    __shared__ unsigned short Bs[256 * 40];
    int t = threadIdx.x;
    int lane = t & 63;
    int w = t >> 6;
    int wr = w >> 1, wc = w & 1;
    int bm = blockIdx.x * 64;
    int l15 = lane & 15, quad = lane >> 4;
    f32x4 acc[2][8];
#pragma unroll
    for (int i = 0; i < 2; ++i)
#pragma unroll
        for (int j = 0; j < 8; ++j) acc[i][j] = (f32x4){0.f, 0.f, 0.f, 0.f};

    for (int k0 = 0; k0 < K; k0 += 32) {
        {
            int m = t >> 2, c = t & 3;
            int gm = bm + m;
            uint4 v = make_uint4(0u, 0u, 0u, 0u);
            if (gm < M) v = *(const uint4*)&A[(size_t)gm * K + k0 + c * 8];
            *(uint4*)&As[m * 40 + c * 8] = v;
        }
#pragma unroll
        for (int i = 0; i < 4; ++i) {
            int cid = t + 256 * i;
            int n = cid >> 2, c = cid & 3;
            uint4 v = *(const uint4*)&Bt[(size_t)n * K + k0 + c * 8];
            *(uint4*)&Bs[n * 40 + c * 8] = v;
        }
        __syncthreads();
        short8 a0 = *(const short8*)&As[(wr * 32 + l15) * 40 + quad * 8];
        short8 a1 = *(const short8*)&As[(wr * 32 + 16 + l15) * 40 + quad * 8];
#pragma unroll
        for (int tt = 0; tt < 8; ++tt) {
            short8 b = *(const short8*)&Bs[(wc * 128 + tt * 16 + l15) * 40 + quad * 8];
            acc[0][tt] = __builtin_amdgcn_mfma_f32_16x16x32_bf16(a0, b, acc[0][tt], 0, 0, 0);
            acc[1][tt] = __builtin_amdgcn_mfma_f32_16x16x32_bf16(a1, b, acc[1][tt], 0, 0, 0);
        }
        __syncthreads();
    }
    int fb = flags[1];
    float drow[2][4];
#pragma unroll
    for (int sa = 0; sa < 2; ++sa)
#pragma unroll
        for (int r = 0; r < 4; ++r) {
            int row = bm + wr * 32 + sa * 16 + quad * 4 + r;
            drow[sa][r] = (rowscale && row < M) ? rowscale[row] : 1.f;
        }
    float bcol[8];
#pragma unroll
    for (int tt = 0; tt < 8; ++tt)
        bcol[tt] = bias ? LF(bias, wc * 128 + tt * 16 + l15, fb) : 0.f;
#pragma unroll
    for (int sa = 0; sa < 2; ++sa)
#pragma unroll
        for (int tt = 0; tt < 8; ++tt)
#pragma unroll
            for (int r = 0; r < 4; ++r) {
                int row = bm + wr * 32 + sa * 16 + quad * 4 + r;
                int colc = wc * 128 + tt * 16 + l15;
                if (row < M) {
                    float v = fmaf(acc[sa][tt][r], drow[sa][r], bcol[tt]);
                    if (relu) v = fmaxf(v, 0.f);
                    C[(size_t)row * 256 + colc] = f2b(v);
                }
            }
}

// ---- XCD-pinned panel aggregation, 128-feat table (layer 1, pre-GEMM) ----
// 4 panels x 32 feats; out[i] = sum_nb xs[c] + xs[i]; 16-lane groups, ushort2/lane
__global__ __launch_bounds__(256) void k_agg2p(const unsigned short* __restrict__ XS,
                                               const int* __restrict__ rowptr, const int* __restrict__ col,
                                               unsigned short* __restrict__ Hout, int* __restrict__ work,
                                               int N) {
    __shared__ int sChunk;
    int xcd = my_xcd();
    int t = threadIdx.x;
    int gi = t >> 4;       // 16 groups of 16 lanes
    int l = t & 15;
    int nch = (N + AGG_CHUNK - 1) / AGG_CHUNK;
    for (int q = 0; q < 4; ++q) {
        int p = (xcd + q) & 3;
        int fo = p * 32 + l * 2;
        while (true) {
            __syncthreads();
            if (t == 0) sChunk = atomicAdd(&work[p], 1);
            __syncthreads();
            int chunk = sChunk;
            if (chunk >= nch) break;
            int node0 = chunk * AGG_CHUNK;
#pragma unroll
            for (int it = 0; it < AGG_CHUNK / 16; ++it) {
                int node = node0 + it * 16 + gi;
                if (node >= N) continue;
                ushort2 sv = *(const ushort2*)&XS[(size_t)node * 128 + fo];
                float ax = b2f(sv.x), ay = b2f(sv.y);
                int s = rowptr[node], e = rowptr[node + 1];
                int j = s;
                for (; j + 4 <= e; j += 4) {
                    int c0 = col[j], c1 = col[j + 1], c2 = col[j + 2], c3 = col[j + 3];
                    ushort2 v0 = *(const ushort2*)&XS[(size_t)c0 * 128 + fo];
                    ushort2 v1 = *(const ushort2*)&XS[(size_t)c1 * 128 + fo];
                    ushort2 v2 = *(const ushort2*)&XS[(size_t)c2 * 128 + fo];
                    ushort2 v3 = *(const ushort2*)&XS[(size_t)c3 * 128 + fo];
                    ax += b2f(v0.x) + b2f(v1.x) + b2f(v2.x) + b2f(v3.x);
                    ay += b2f(v0.y) + b2f(v1.y) + b2f(v2.y) + b2f(v3.y);
                }
                for (; j < e; ++j) {
                    ushort2 v = *(const ushort2*)&XS[(size_t)col[j] * 128 + fo];
                    ax += b2f(v.x); ay += b2f(v.y);
                }
                ushort2 o;
                o.x = f2b(ax); o.y = f2b(ay);
                *(ushort2*)&Hout[(size_t)node * 128 + fo] = o;
            }
        }
    }
}

// ---- XCD-pinned panel aggregation, 256-feat table (layer 2, post-GEMM) ----
// 8 panels x 32 feats; out[i] = dinv[i]*(sum_nb XW[c] + XW[i]) + bias
__global__ __launch_bounds__(256) void k_agg4p(const unsigned short* __restrict__ XW,
                                               const int* __restrict__ rowptr, const int* __restrict__ col,
                                               const float* __restrict__ dinv, const void* __restrict__ bias,
                                               const int* __restrict__ flags,
                                               unsigned short* __restrict__ Hout, int* __restrict__ work,
                                               int N) {
    __shared__ int sChunk;
    int xcd = my_xcd();
    int t = threadIdx.x;
    int gi = t >> 4;
    int l = t & 15;
    int fb = flags[1];
    int nch = (N + AGG_CHUNK - 1) / AGG_CHUNK;
    for (int q = 0; q < 8; ++q) {
        int p = (xcd + q) & 7;
        int fo = p * 32 + l * 2;
        float bx = LF(bias, fo + 0, fb), by = LF(bias, fo + 1, fb);
        while (true) {
            __syncthreads();
            if (t == 0) sChunk = atomicAdd(&work[p], 1);
            __syncthreads();
            int chunk = sChunk;
            if (chunk >= nch) break;
            int node0 = chunk * AGG_CHUNK;
#pragma unroll
            for (int it = 0; it < AGG_CHUNK / 16; ++it) {
                int node = node0 + it * 16 + gi;
                if (node >= N) continue;
                ushort2 sv = *(const ushort2*)&XW[(size_t)node * 256 + fo];
                float ax = b2f(sv.x), ay = b2f(sv.y);
                int s = rowptr[node], e = rowptr[node + 1];
                int j = s;
                for (; j + 4 <= e; j += 4) {
                    int c0 = col[j], c1 = col[j + 1], c2 = col[j + 2], c3 = col[j + 3];
                    ushort2 v0 = *(const ushort2*)&XW[(size_t)c0 * 256 + fo];
                    ushort2 v1 = *(const ushort2*)&XW[(size_t)c1 * 256 + fo];
                    ushort2 v2 = *(const ushort2*)&XW[(size_t)c2 * 256 + fo];
                    ushort2 v3 = *(const ushort2*)&XW[(size_t)c3 * 256 + fo];
                    ax += b2f(v0.x) + b2f(v1.x) + b2f(v2.x) + b2f(v3.x);
                    ay += b2f(v0.y) + b2f(v1.y) + b2f(v2.y) + b2f(v3.y);
                }
                for (; j < e; ++j) {
                    ushort2 v = *(const ushort2*)&XW[(size_t)col[j] * 256 + fo];
                    ax += b2f(v.x); ay += b2f(v.y);
                }
                float di = dinv[node];
                ushort2 o;
                o.x = f2b(fmaf(ax, di, bx));
                o.y = f2b(fmaf(ay, di, by));
                *(ushort2*)&Hout[(size_t)node * 256 + fo] = o;
            }
        }
    }
}

// ---- segment-mean pool over sorted batch ranges: one block per graph ----
__global__ __launch_bounds__(256) void k_pool(const unsigned short* __restrict__ H2,
                                              const int* __restrict__ gstart,
                                              float* __restrict__ pooled) {
    __shared__ float red[4][256];
    int g = blockIdx.x, t = threadIdx.x;
    int sub = t >> 6, lane = t & 63;
    int s = gstart[g], e = gstart[g + 1];
    int cnt = e - s;
    float ax = 0.f, ay = 0.f, az = 0.f, aw = 0.f;
    for (int i = s + sub; i < e; i += 4) {
        ushort4 v = *(const ushort4*)&H2[(size_t)i * 256 + lane * 4];
        ax += b2f(v.x); ay += b2f(v.y); az += b2f(v.z); aw += b2f(v.w);
    }
    red[sub][lane * 4 + 0] = ax;
    red[sub][lane * 4 + 1] = ay;
    red[sub][lane * 4 + 2] = az;
    red[sub][lane * 4 + 3] = aw;
    __syncthreads();
    float inv = 1.f / fmaxf((float)cnt, 1.f);
    pooled[(size_t)g * 256 + t] = (red[0][t] + red[1][t] + red[2][t] + red[3][t]) * inv;
}

// ---- classifier ----
__global__ void k_final(const float* __restrict__ pooled, const void* __restrict__ Wlin,
                        const void* __restrict__ blin, const int* __restrict__ flags,
                        void* __restrict__ outv) {
    __shared__ float p[HID];
    int g = blockIdx.x, t = threadIdx.x, fb = flags[1];
    p[t] = pooled[(size_t)g * HID + t];
    __syncthreads();
    if (t < N_CLS) {
        float s = LF(blin, t, fb);
        for (int f = 0; f < HID; ++f) s = fmaf(p[f], LF(Wlin, f * N_CLS + t, fb), s);
        if (fb) ((bf16*)outv)[g * N_CLS + t] = __float2bfloat16(s);
        else    ((float*)outv)[g * N_CLS + t] = s;
    }
}

extern "C" void kernel_launch(void* const* d_in, const int* in_sizes, int n_in,
                              void* d_out, int out_size, void* d_ws, size_t ws_size,
                              hipStream_t stream) {
    (void)n_in; (void)ws_size; (void)in_sizes; (void)out_size;
    const void* x     = d_in[0];
    const int*  ei    = (const int*)d_in[1];
    const int*  batch = (const int*)d_in[2];
    const void* W1    = d_in[3];
    const void* b1    = d_in[4];
    const void* W2    = d_in[5];
    const void* b2    = d_in[6];
    const void* Wl    = d_in[7];
    const void* bl    = d_in[8];

    const int N = N_NODES, E = N_EDGES, F = IN_F, H = HID, G = N_GRAPH;

    char* ws = (char*)d_ws;
    size_t off = 0;
    auto alloc = [&](size_t bytes) -> void* {
        void* p = ws + off;
        off += (bytes + 511) & ~(size_t)511;
        return p;
    };
    unsigned short* xs   = (unsigned short*)alloc((size_t)N * F * 2);  // prescaled x, bf16
    unsigned short* aggX = (unsigned short*)alloc((size_t)N * F * 2);  // A-partial @ x
    unsigned short* H1   = (unsigned short*)alloc((size_t)N * H * 2);
    unsigned short* H2   = (unsigned short*)alloc((size_t)N * H * 2);
    unsigned short* XW2s = xs;  // aliases xs+aggX (both dead after GEMM1)
    unsigned short* w1t  = (unsigned short*)alloc((size_t)H * F * 2);
    unsigned short* w2t  = (unsigned short*)alloc((size_t)H * H * 2);
    float* pooled  = (float*)alloc((size_t)G * H * 4);
    int*   deg8    = (int*)alloc((size_t)8 * N * 4);   // zero region start
    int*   workA   = (int*)alloc(256);                 // agg4p queues (8)
    int*   workB   = (int*)alloc(256);                 // agg2p queues (4) ; zero region end
    int*   total   = (int*)alloc(512);
    int*   base8   = (int*)alloc((size_t)8 * N * 4);
    int*   deg     = (int*)alloc((size_t)N * 4);
    int*   gstart  = (int*)alloc((size_t)(G + 1) * 4);
    float* dinv    = (float*)alloc((size_t)N * 4);
    int*   rowptr  = (int*)alloc((size_t)(N + 1) * 4);
    int*   blockSum = (int*)alloc(256 * 4);
    int*   blockOff = (int*)alloc(256 * 4);
    int*   flags   = (int*)alloc(512);
    int*   col     = (int*)alloc((size_t)E * 4);
    size_t zero_bytes = (size_t)((char*)total - (char*)deg8);

    hipMemsetAsync(deg8, 0, zero_bytes, stream);

    int nbE = (E + 255) / 256;
    int nbN = (N + 255) / 256;

    k_detect<<<1, 256, 0, stream>>>(ei, (const unsigned short*)x, flags);
    k_deg<<<nbE, 256, 0, stream>>>(ei, deg8, flags, E, N);
    k_sum<<<(N + 256) / 256, 256, 0, stream>>>(deg8, deg, dinv, batch, flags, gstart, N, G);
    k_scan1<<<nbN, 256, 0, stream>>>(deg, rowptr, blockSum, N);
    k_scan2<<<1, 256, 0, stream>>>(blockSum, blockOff, total, nbN);
    k_scan3<<<nbN, 256, 0, stream>>>(rowptr, blockOff, N, total);
    k_base<<<nbN, 256, 0, stream>>>(rowptr, deg8, base8, N);
    k_fill<<<nbE, 256, 0, stream>>>(ei, base8, col, flags, E, N);

    // conversions: prescaled x, transposed weights
    k_cvtx<<<(N * F / 4 + 255) / 256, 256, 0, stream>>>(x, dinv, xs, flags, N * F / 4);
    k_cvtT<<<(F * 256 + 255) / 256, 256, 0, stream>>>(W1, w1t, flags, F, 7);
    k_cvtT<<<(H * 256 + 255) / 256, 256, 0, stream>>>(W2, w2t, flags, H, 8);

    int gemmGrid = (N + 63) / 64;

    // layer 1: panel-aggregate raw features, then GEMM with dinv-scale + bias + relu
    k_agg2p<<<AGG_GRID, 256, 0, stream>>>(xs, rowptr, col, aggX, workB, N);
    k_gemm<<<gemmGrid, 256, 0, stream>>>(aggX, w1t, H1, N, F, dinv, b1, flags, 1);
    // layer 2: GEMM with dinv-scale epilogue, then panel-aggregate + scale + bias
    k_gemm<<<gemmGrid, 256, 0, stream>>>(H1, w2t, XW2s, N, H, dinv, nullptr, flags, 0);
    k_agg4p<<<AGG_GRID, 256, 0, stream>>>(XW2s, rowptr, col, dinv, b2, flags, H2, workA, N);
    // pool + classify
    k_pool<<<G, 256, 0, stream>>>(H2, gstart, pooled);
    k_final<<<G, 256, 0, stream>>>(pooled, Wl, bl, flags, d_out);
}

// Round 8
// 393.216 us; speedup vs baseline: 1.9406x; 1.9406x over previous
//
#include <hip/hip_runtime.h>
#include <hip/hip_bf16.h>

typedef __hip_bfloat16 bf16;
typedef __attribute__((ext_vector_type(8))) short short8;
typedef __attribute__((ext_vector_type(4))) float f32x4;

// ---- problem constants (fixed by reference file) ----
#define N_NODES 50000
#define N_EDGES 800000
#define IN_F    128
#define HID     256
#define N_CLS   10
#define N_GRAPH 256

// flags[0] = ints are int64 (read low words), flags[1] = floats are bf16
__device__ __forceinline__ int IG(const int* __restrict__ p, int i, int w) {
    return w ? p[2 * i] : p[i];
}
__device__ __forceinline__ float LF(const void* __restrict__ p, int i, int isbf) {
    return isbf ? __bfloat162float(((const bf16*)p)[i]) : ((const float*)p)[i];
}
__device__ __forceinline__ float b2f(unsigned short h) {
    union { unsigned u; float f; } c; c.u = ((unsigned)h) << 16; return c.f;
}
__device__ __forceinline__ unsigned short f2b(float x) {
    bf16 h = __float2bfloat16(x);
    union { bf16 b; unsigned short u; } c; c.b = h; return c.u;
}

// ---- combined dtype detectors (1 block) ----
__global__ __launch_bounds__(256) void k_detect(const int* __restrict__ ei,
                                                const unsigned short* __restrict__ x,
                                                int* __restrict__ flags) {
    __shared__ int nz, cnt;
    if (threadIdx.x == 0) { nz = 0; cnt = 0; }
    __syncthreads();
    int found = 0, c = 0;
    for (int s = 0; s < 4; ++s) {
        int idx = 2 * (threadIdx.x * 4 + s) + 1;
        if (ei[idx] != 0) found = 1;
    }
    for (int s = 0; s < 8; ++s) {
        unsigned short h = x[threadIdx.x * 8 + s];
        int e = (h >> 7) & 0xFF;
        if (e >= 110 && e <= 135) c++;
    }
    if (found) atomicAdd(&nz, 1);
    atomicAdd(&cnt, c);
    __syncthreads();
    if (threadIdx.x == 0) {
        flags[0] = (nz == 0) ? 1 : 0;
        flags[1] = (cnt > 1536) ? 1 : 0;
    }
}

// ---- degree count over dst, privatized 8-way by pseudo-XCD = blockIdx&7 ----
__global__ __launch_bounds__(256) void k_deg(const int* __restrict__ ei, int* __restrict__ deg8,
                                             const int* __restrict__ flags, int E, int N) {
    int e = blockIdx.x * 256 + threadIdx.x;
    int w = flags[0];
    int px = blockIdx.x & 7;
    if (e < E) {
        int d = IG(ei, E + e, w);
        int s = IG(ei, e, w);
        if ((unsigned)d < (unsigned)N && (unsigned)s < (unsigned)N)
            atomicAdd(&deg8[px * N + d], 1);
    }
}

// ---- sum deg8 -> deg, dinv; plus graph boundaries from sorted batch ----
__global__ __launch_bounds__(256) void k_sum(const int* __restrict__ deg8, int* __restrict__ deg,
                                             float* __restrict__ dinv, const int* __restrict__ batch,
                                             const int* __restrict__ flags, int* __restrict__ gstart,
                                             int N, int G) {
    int i = blockIdx.x * 256 + threadIdx.x;
    int w = flags[0];
    if (i < N) {
        int d = 0;
#pragma unroll
        for (int x = 0; x < 8; ++x) d += deg8[x * N + i];
        deg[i] = d;
        dinv[i] = rsqrtf((float)(d + 1));  // +1 self loop
    }
    if (i <= N) {
        int prev = (i == 0) ? -1 : IG(batch, i - 1, w);
        int cur  = (i == N) ? G : IG(batch, i, w);
        if (prev < -1) prev = -1;
        if (cur > G) cur = G;
        for (int g = prev + 1; g <= cur; ++g)
            if (g >= 0 && g <= G) gstart[g] = i;
    }
}

// ---- exclusive scan over degrees ----
__global__ __launch_bounds__(256) void k_scan1(const int* __restrict__ deg, int* __restrict__ rowptr,
                                               int* __restrict__ blockSum, int N) {
    __shared__ int s[256];
    int t = threadIdx.x;
    int i = blockIdx.x * 256 + t;
    int v = (i < N) ? deg[i] : 0;
    s[t] = v;
    __syncthreads();
    for (int off = 1; off < 256; off <<= 1) {
        int add = (t >= off) ? s[t - off] : 0;
        __syncthreads();
        s[t] += add;
        __syncthreads();
    }
    if (i < N) rowptr[i] = s[t] - v;
    if (t == 255) blockSum[blockIdx.x] = s[t];
}

__global__ __launch_bounds__(256) void k_scan2(const int* __restrict__ blockSum, int* __restrict__ blockOff,
                                               int* __restrict__ total, int nb) {
    __shared__ int s[256];
    int t = threadIdx.x;
    int v = (t < nb) ? blockSum[t] : 0;
    s[t] = v;
    __syncthreads();
    for (int off = 1; off < 256; off <<= 1) {
        int add = (t >= off) ? s[t - off] : 0;
        __syncthreads();
        s[t] += add;
        __syncthreads();
    }
    blockOff[t] = s[t] - v;
    if (t == 255) total[0] = s[255];
}

// ---- scan finalize + per-(pseudo-xcd,node) fill bases, merged ----
__global__ __launch_bounds__(256) void k_scan3b(int* __restrict__ rowptr, const int* __restrict__ blockOff,
                                                const int* __restrict__ deg8, int* __restrict__ base8,
                                                int N, const int* __restrict__ total) {
    int i = blockIdx.x * 256 + threadIdx.x;
    if (i < N) {
        int r = rowptr[i] + blockOff[blockIdx.x];
        rowptr[i] = r;
        int b = r;
#pragma unroll
        for (int x = 0; x < 8; ++x) {
            base8[x * N + i] = b;
            b += deg8[x * N + i];
        }
    }
    if (i == 0) rowptr[N] = total[0];
}

// ---- CSR fill: position from privatized base (per-px slot ranges, no overlap) ----
__global__ __launch_bounds__(256) void k_fill(const int* __restrict__ ei, int* __restrict__ base8,
                                              int* __restrict__ col, const int* __restrict__ flags,
                                              int E, int N) {
    int e = blockIdx.x * 256 + threadIdx.x;
    int w = flags[0];
    int px = blockIdx.x & 7;
    if (e < E) {
        int d = IG(ei, E + e, w);
        int s = IG(ei, e, w);
        if ((unsigned)d < (unsigned)N && (unsigned)s < (unsigned)N) {
            int pos = atomicAdd(&base8[px * N + d], 1);
            col[pos] = s;
        }
    }
}

// ---- merged conversions: xs = x*dinv (bf16), w1t = W1^T, w2t = W2^T ----
#define CVTX_BLOCKS 6250   // N*IN_F/4 / 256
#define CVT1_BLOCKS 128    // IN_F*256 / 256
#define CVT2_BLOCKS 256    // HID*256 / 256
__global__ __launch_bounds__(256) void k_cvt(const void* __restrict__ x, const float* __restrict__ dinv,
                                             unsigned short* __restrict__ xs,
                                             const void* __restrict__ W1, unsigned short* __restrict__ w1t,
                                             const void* __restrict__ W2, unsigned short* __restrict__ w2t,
                                             const int* __restrict__ flags) {
    int b = blockIdx.x;
    int fb = flags[1];
    if (b < CVTX_BLOCKS) {
        int gid = b * 256 + threadIdx.x;
        int row = gid >> 5;  // 32 4-elem chunks per 128-feat row
        float d = dinv[row];
        ushort4 o;
        if (fb) {
            ushort4 v = ((const ushort4*)x)[gid];
            o.x = f2b(b2f(v.x) * d); o.y = f2b(b2f(v.y) * d);
            o.z = f2b(b2f(v.z) * d); o.w = f2b(b2f(v.w) * d);
        } else {
            float4 v = ((const float4*)x)[gid];
            o.x = f2b(v.x * d); o.y = f2b(v.y * d);
            o.z = f2b(v.z * d); o.w = f2b(v.w * d);
        }
        ((ushort4*)xs)[gid] = o;
    } else if (b < CVTX_BLOCKS + CVT1_BLOCKS) {
        int i = (b - CVTX_BLOCKS) * 256 + threadIdx.x;
        int n = i >> 7, k = i & 127;
        w1t[i] = f2b(LF(W1, k * 256 + n, fb));
    } else {
        int i = (b - CVTX_BLOCKS - CVT1_BLOCKS) * 256 + threadIdx.x;
        int n = i >> 8, k = i & 255;
        w2t[i] = f2b(LF(W2, k * 256 + n, fb));
    }
}

// ---- bf16 MFMA GEMM: C[M x 256] = A[M x K] @ B[K x 256] with fused epilogue ----
__global__ __launch_bounds__(256) void k_gemm(const unsigned short* __restrict__ A,
                                              const unsigned short* __restrict__ Bt,
                                              unsigned short* __restrict__ C, int M, int K,
                                              const float* __restrict__ rowscale,
                                              const void* __restrict__ bias,
                                              const int* __restrict__ flags, int relu) {
    __shared__ unsigned short As[64 * 40];
    __shared__ unsigned short Bs[256 * 40];
    int t = threadIdx.x;
    int lane = t & 63;
    int w = t >> 6;
    int wr = w >> 1, wc = w & 1;
    int bm = blockIdx.x * 64;
    int l15 = lane & 15, quad = lane >> 4;
    f32x4 acc[2][8];
#pragma unroll
    for (int i = 0; i < 2; ++i)
#pragma unroll
        for (int j = 0; j < 8; ++j) acc[i][j] = (f32x4){0.f, 0.f, 0.f, 0.f};

    for (int k0 = 0; k0 < K; k0 += 32) {
        {
            int m = t >> 2, c = t & 3;
            int gm = bm + m;
            uint4 v = make_uint4(0u, 0u, 0u, 0u);
            if (gm < M) v = *(const uint4*)&A[(size_t)gm * K + k0 + c * 8];
            *(uint4*)&As[m * 40 + c * 8] = v;
        }
#pragma unroll
        for (int i = 0; i < 4; ++i) {
            int cid = t + 256 * i;
            int n = cid >> 2, c = cid & 3;
            uint4 v = *(const uint4*)&Bt[(size_t)n * K + k0 + c * 8];
            *(uint4*)&Bs[n * 40 + c * 8] = v;
        }
        __syncthreads();
        short8 a0 = *(const short8*)&As[(wr * 32 + l15) * 40 + quad * 8];
        short8 a1 = *(const short8*)&As[(wr * 32 + 16 + l15) * 40 + quad * 8];
#pragma unroll
        for (int tt = 0; tt < 8; ++tt) {
            short8 b = *(const short8*)&Bs[(wc * 128 + tt * 16 + l15) * 40 + quad * 8];
            acc[0][tt] = __builtin_amdgcn_mfma_f32_16x16x32_bf16(a0, b, acc[0][tt], 0, 0, 0);
            acc[1][tt] = __builtin_amdgcn_mfma_f32_16x16x32_bf16(a1, b, acc[1][tt], 0, 0, 0);
        }
        __syncthreads();
    }
    int fb = flags[1];
    float drow[2][4];
#pragma unroll
    for (int sa = 0; sa < 2; ++sa)
#pragma unroll
        for (int r = 0; r < 4; ++r) {
            int row = bm + wr * 32 + sa * 16 + quad * 4 + r;
            drow[sa][r] = (rowscale && row < M) ? rowscale[row] : 1.f;
        }
    float bcol[8];
#pragma unroll
    for (int tt = 0; tt < 8; ++tt)
        bcol[tt] = bias ? LF(bias, wc * 128 + tt * 16 + l15, fb) : 0.f;
#pragma unroll
    for (int sa = 0; sa < 2; ++sa)
#pragma unroll
        for (int tt = 0; tt < 8; ++tt)
#pragma unroll
            for (int r = 0; r < 4; ++r) {
                int row = bm + wr * 32 + sa * 16 + quad * 4 + r;
                int colc = wc * 128 + tt * 16 + l15;
                if (row < M) {
                    float v = fmaf(acc[sa][tt][r], drow[sa][r], bcol[tt]);
                    if (relu) v = fmaxf(v, 0.f);
                    C[(size_t)row * 256 + colc] = f2b(v);
                }
            }
}

// ---- agg over 128-feat prescaled rows: out[i] = sum_nb xs[c] + xs[i] ----
// one wave per node, lane = 2 features; 16/8/4/1 cascade for MLP
__global__ __launch_bounds__(256) void k_agg2(const unsigned short* __restrict__ XS,
                                              const int* __restrict__ rowptr, const int* __restrict__ col,
                                              unsigned short* __restrict__ Hout, int N) {
    int lane = threadIdx.x & 63;
    int i = (blockIdx.x * 256 + threadIdx.x) >> 6;
    if (i >= N) return;
    int fo = lane * 2;
    ushort2 sv = *(const ushort2*)&XS[(size_t)i * 128 + fo];
    float ax = b2f(sv.x), ay = b2f(sv.y);
    int s = rowptr[i], e = rowptr[i + 1];
    int j = s;
    while (j + 16 <= e) {
        ushort2 v[16];
#pragma unroll
        for (int q = 0; q < 16; ++q)
            v[q] = *(const ushort2*)&XS[(size_t)col[j + q] * 128 + fo];
#pragma unroll
        for (int q = 0; q < 16; ++q) { ax += b2f(v[q].x); ay += b2f(v[q].y); }
        j += 16;
    }
    if (j + 8 <= e) {
        ushort2 v[8];
#pragma unroll
        for (int q = 0; q < 8; ++q)
            v[q] = *(const ushort2*)&XS[(size_t)col[j + q] * 128 + fo];
#pragma unroll
        for (int q = 0; q < 8; ++q) { ax += b2f(v[q].x); ay += b2f(v[q].y); }
        j += 8;
    }
    if (j + 4 <= e) {
        ushort2 v[4];
#pragma unroll
        for (int q = 0; q < 4; ++q)
            v[q] = *(const ushort2*)&XS[(size_t)col[j + q] * 128 + fo];
#pragma unroll
        for (int q = 0; q < 4; ++q) { ax += b2f(v[q].x); ay += b2f(v[q].y); }
        j += 4;
    }
    for (; j < e; ++j) {
        ushort2 v = *(const ushort2*)&XS[(size_t)col[j] * 128 + fo];
        ax += b2f(v.x); ay += b2f(v.y);
    }
    ushort2 o;
    o.x = f2b(ax); o.y = f2b(ay);
    *(ushort2*)&Hout[(size_t)i * 128 + fo] = o;
}

// ---- agg over 256-feat prescaled rows with scale+bias epilogue ----
// out[i] = dinv[i]*(sum_nb XW[c] + XW[i]) + bias; one wave per node, lane = 4 feats
__global__ __launch_bounds__(256) void k_agg4(const unsigned short* __restrict__ XW,
                                              const int* __restrict__ rowptr, const int* __restrict__ col,
                                              const float* __restrict__ dinv, const void* __restrict__ bias,
                                              const int* __restrict__ flags,
                                              unsigned short* __restrict__ Hout, int N) {
    int lane = threadIdx.x & 63;
    int i = (blockIdx.x * 256 + threadIdx.x) >> 6;
    if (i >= N) return;
    int fo = lane * 4;
    ushort4 sv = *(const ushort4*)&XW[(size_t)i * 256 + fo];
    float ax = b2f(sv.x), ay = b2f(sv.y), az = b2f(sv.z), aw = b2f(sv.w);
    int s = rowptr[i], e = rowptr[i + 1];
    int j = s;
    while (j + 16 <= e) {
        ushort4 v[16];
#pragma unroll
        for (int q = 0; q < 16; ++q)
            v[q] = *(const ushort4*)&XW[(size_t)col[j + q] * 256 + fo];
#pragma unroll
        for (int q = 0; q < 16; ++q) {
            ax += b2f(v[q].x); ay += b2f(v[q].y);
            az += b2f(v[q].z); aw += b2f(v[q].w);
        }
        j += 16;
    }
    if (j + 8 <= e) {
        ushort4 v[8];
#pragma unroll
        for (int q = 0; q < 8; ++q)
            v[q] = *(const ushort4*)&XW[(size_t)col[j + q] * 256 + fo];
#pragma unroll
        for (int q = 0; q < 8; ++q) {
            ax += b2f(v[q].x); ay += b2f(v[q].y);
            az += b2f(v[q].z); aw += b2f(v[q].w);
        }
        j += 8;
    }
    if (j + 4 <= e) {
        ushort4 v[4];
#pragma unroll
        for (int q = 0; q < 4; ++q)
            v[q] = *(const ushort4*)&XW[(size_t)col[j + q] * 256 + fo];
#pragma unroll
        for (int q = 0; q < 4; ++q) {
            ax += b2f(v[q].x); ay += b2f(v[q].y);
            az += b2f(v[q].z); aw += b2f(v[q].w);
        }
        j += 4;
    }
    for (; j < e; ++j) {
        ushort4 v = *(const ushort4*)&XW[(size_t)col[j] * 256 + fo];
        ax += b2f(v.x); ay += b2f(v.y); az += b2f(v.z); aw += b2f(v.w);
    }
    int fb = flags[1];
    float di = dinv[i];
    float bx = LF(bias, fo + 0, fb), by = LF(bias, fo + 1, fb);
    float bz = LF(bias, fo + 2, fb), bw = LF(bias, fo + 3, fb);
    ushort4 o;
    o.x = f2b(fmaf(ax, di, bx)); o.y = f2b(fmaf(ay, di, by));
    o.z = f2b(fmaf(az, di, bz)); o.w = f2b(fmaf(aw, di, bw));
    *(ushort4*)&Hout[(size_t)i * 256 + fo] = o;
}

// ---- segment-mean pool over sorted batch ranges: one block per graph ----
__global__ __launch_bounds__(256) void k_pool(const unsigned short* __restrict__ H2,
                                              const int* __restrict__ gstart,
                                              float* __restrict__ pooled) {
    __shared__ float red[4][256];
    int g = blockIdx.x, t = threadIdx.x;
    int sub = t >> 6, lane = t & 63;
    int s = gstart[g], e = gstart[g + 1];
    int cnt = e - s;
    float ax = 0.f, ay = 0.f, az = 0.f, aw = 0.f;
    for (int i = s + sub; i < e; i += 4) {
        ushort4 v = *(const ushort4*)&H2[(size_t)i * 256 + lane * 4];
        ax += b2f(v.x); ay += b2f(v.y); az += b2f(v.z); aw += b2f(v.w);
    }
    red[sub][lane * 4 + 0] = ax;
    red[sub][lane * 4 + 1] = ay;
    red[sub][lane * 4 + 2] = az;
    red[sub][lane * 4 + 3] = aw;
    __syncthreads();
    float inv = 1.f / fmaxf((float)cnt, 1.f);
    pooled[(size_t)g * 256 + t] = (red[0][t] + red[1][t] + red[2][t] + red[3][t]) * inv;
}

// ---- classifier ----
__global__ void k_final(const float* __restrict__ pooled, const void* __restrict__ Wlin,
                        const void* __restrict__ blin, const int* __restrict__ flags,
                        void* __restrict__ outv) {
    __shared__ float p[HID];
    int g = blockIdx.x, t = threadIdx.x, fb = flags[1];
    p[t] = pooled[(size_t)g * HID + t];
    __syncthreads();
    if (t < N_CLS) {
        float s = LF(blin, t, fb);
        for (int f = 0; f < HID; ++f) s = fmaf(p[f], LF(Wlin, f * N_CLS + t, fb), s);
        if (fb) ((bf16*)outv)[g * N_CLS + t] = __float2bfloat16(s);
        else    ((float*)outv)[g * N_CLS + t] = s;
    }
}

extern "C" void kernel_launch(void* const* d_in, const int* in_sizes, int n_in,
                              void* d_out, int out_size, void* d_ws, size_t ws_size,
                              hipStream_t stream) {
    (void)n_in; (void)ws_size; (void)in_sizes; (void)out_size;
    const void* x     = d_in[0];
    const int*  ei    = (const int*)d_in[1];
    const int*  batch = (const int*)d_in[2];
    const void* W1    = d_in[3];
    const void* b1    = d_in[4];
    const void* W2    = d_in[5];
    const void* b2    = d_in[6];
    const void* Wl    = d_in[7];
    const void* bl    = d_in[8];

    const int N = N_NODES, E = N_EDGES, F = IN_F, H = HID, G = N_GRAPH;

    char* ws = (char*)d_ws;
    size_t off = 0;
    auto alloc = [&](size_t bytes) -> void* {
        void* p = ws + off;
        off += (bytes + 511) & ~(size_t)511;
        return p;
    };
    unsigned short* xs   = (unsigned short*)alloc((size_t)N * F * 2);  // prescaled x, bf16
    unsigned short* aggX = (unsigned short*)alloc((size_t)N * F * 2);  // A-partial @ x
    unsigned short* H1   = (unsigned short*)alloc((size_t)N * H * 2);
    unsigned short* H2   = (unsigned short*)alloc((size_t)N * H * 2);
    unsigned short* XW2s = xs;  // aliases xs+aggX (both dead after GEMM1)
    unsigned short* w1t  = (unsigned short*)alloc((size_t)H * F * 2);
    unsigned short* w2t  = (unsigned short*)alloc((size_t)H * H * 2);
    float* pooled  = (float*)alloc((size_t)G * H * 4);
    int*   deg8    = (int*)alloc((size_t)8 * N * 4);   // zero region (only deg8)
    int*   total   = (int*)alloc(512);
    int*   base8   = (int*)alloc((size_t)8 * N * 4);
    int*   deg     = (int*)alloc((size_t)N * 4);
    int*   gstart  = (int*)alloc((size_t)(G + 1) * 4);
    float* dinv    = (float*)alloc((size_t)N * 4);
    int*   rowptr  = (int*)alloc((size_t)(N + 1) * 4);
    int*   blockSum = (int*)alloc(256 * 4);
    int*   blockOff = (int*)alloc(256 * 4);
    int*   flags   = (int*)alloc(512);
    int*   col     = (int*)alloc((size_t)E * 4);
    size_t zero_bytes = (size_t)((char*)total - (char*)deg8);

    hipMemsetAsync(deg8, 0, zero_bytes, stream);

    int nbE = (E + 255) / 256;
    int nbN = (N + 255) / 256;

    k_detect<<<1, 256, 0, stream>>>(ei, (const unsigned short*)x, flags);
    k_deg<<<nbE, 256, 0, stream>>>(ei, deg8, flags, E, N);
    k_sum<<<(N + 256) / 256, 256, 0, stream>>>(deg8, deg, dinv, batch, flags, gstart, N, G);
    k_scan1<<<nbN, 256, 0, stream>>>(deg, rowptr, blockSum, N);
    k_scan2<<<1, 256, 0, stream>>>(blockSum, blockOff, total, nbN);
    k_scan3b<<<nbN, 256, 0, stream>>>(rowptr, blockOff, deg8, base8, N, total);
    k_fill<<<nbE, 256, 0, stream>>>(ei, base8, col, flags, E, N);

    // merged conversions (prescaled x + both transposed weights)
    k_cvt<<<CVTX_BLOCKS + CVT1_BLOCKS + CVT2_BLOCKS, 256, 0, stream>>>(
        x, dinv, xs, W1, w1t, W2, w2t, flags);

    int gemmGrid = (N + 63) / 64;
    int nbAgg = (N + 3) / 4;

    // layer 1: aggregate raw features, then GEMM with dinv-scale + bias + relu
    k_agg2<<<nbAgg, 256, 0, stream>>>(xs, rowptr, col, aggX, N);
    k_gemm<<<gemmGrid, 256, 0, stream>>>(aggX, w1t, H1, N, F, dinv, b1, flags, 1);
    // layer 2: GEMM with dinv-scale epilogue, then aggregate + scale + bias
    k_gemm<<<gemmGrid, 256, 0, stream>>>(H1, w2t, XW2s, N, H, dinv, nullptr, flags, 0);
    k_agg4<<<nbAgg, 256, 0, stream>>>(XW2s, rowptr, col, dinv, b2, flags, H2, N);
    // pool + classify
    k_pool<<<G, 256, 0, stream>>>(H2, gstart, pooled);
    k_final<<<G, 256, 0, stream>>>(pooled, Wl, bl, flags, d_out);
}